// Round 7
// baseline (82.978 us; speedup 1.0000x reference)
//
#include <hip/hip_runtime.h>

typedef float  f32x4  __attribute__((ext_vector_type(4)));
typedef short  s16x8  __attribute__((ext_vector_type(8)));
typedef short  s16x4  __attribute__((ext_vector_type(4)));

__device__ __forceinline__ unsigned short f2bf(float f) {
    unsigned int u = __float_as_uint(f);
    return (unsigned short)((u + 0x7FFFu + ((u >> 16) & 1u)) >> 16);
}

// pack 8 f32 -> 8 bf16 via 4x v_cvt_pk_bf16_f32 (RNE)
__device__ __forceinline__ s16x8 cvt8(f32x4 a, f32x4 b) {
    union { unsigned int u[4]; s16x8 v; } r;
    asm("v_cvt_pk_bf16_f32 %0, %1, %2" : "=v"(r.u[0]) : "v"(a[0]), "v"(a[1]));
    asm("v_cvt_pk_bf16_f32 %0, %1, %2" : "=v"(r.u[1]) : "v"(a[2]), "v"(a[3]));
    asm("v_cvt_pk_bf16_f32 %0, %1, %2" : "=v"(r.u[2]) : "v"(b[0]), "v"(b[1]));
    asm("v_cvt_pk_bf16_f32 %0, %1, %2" : "=v"(r.u[3]) : "v"(b[2]), "v"(b[3]));
    return r.v;
}

#define GLOAD_LDS16(g, l) __builtin_amdgcn_global_load_lds(                    \
    (const __attribute__((address_space(1))) void*)(g),                        \
    (__attribute__((address_space(3))) void*)(l), 16, 0, 0)

// ---------------------------------------------------------------------------
// Kernel 0: build wt2 = swizzle-tiled bf16 weights.
// Element (n,k): byte = (k>>6)*49152 + n*128 + ((2*(k&63)) ^ ((n&7)<<4)).
// Linear global_load_lds of a tile reproduces the conflict-free swizzled
// LDS layout (inverse-swz source, m173 / rule 21).
// ---------------------------------------------------------------------------
__global__ void prep_wt(const float* __restrict__ Wq,
                        const float* __restrict__ Wk,
                        const float* __restrict__ Wv,
                        unsigned char* __restrict__ wt2) {
    int n = blockIdx.x;                       // 0..383
    const float* W = (n < 128) ? Wq : ((n < 256) ? Wk : Wv);
    int h = n & 127;
    for (int k = threadIdx.x; k < 1024; k += blockDim.x) {
        unsigned short v = f2bf(W[(size_t)k * 128 + h]);
        size_t off = (size_t)(k >> 6) * 49152 + (size_t)n * 128 +
                     (((k & 63) * 2) ^ ((n & 7) << 4));
        *(unsigned short*)(wt2 + off) = v;
    }
}

// ---------------------------------------------------------------------------
// Kernel 1: QKV GEMM with counted-vmcnt pipeline (T3/T4).
// BM=128, BN=384 (x read exactly once), BK=64, grid 256, 512 threads.
// 8 waves as 1M x 8N: wave tile = 128 rows x 48 cols (acc[8][3]); each
// wave's B slab (48 rows of wt2) is WAVE-PRIVATE: staged by its own 6
// global_load_lds, read only by itself -> B readiness is a wave-local
// counted vmcnt, independent of barriers.  A (shared) is reg-staged
// f32->bf16; per-tile issue order [A(t+1) x4 loads ... B(t+1) x6 gloads]
// makes every wait counted: vmcnt(4) => B(t) landed, vmcnt(6) => A(t+1)
// regs ready while B(t+1) stays in flight.  ONE barrier per tile
// (lgkmcnt-only); vmcnt is never drained in steady state.
// LDS 128KB: A 2x16KB bf16 + B 2x48KB, both XOR-swizzled (conflict-free,
// verified 0 conflicts in R5/R6).
// Outputs: Q,K bf16 [B*T][128]; V transposed bf16 [B][128][256].
// ---------------------------------------------------------------------------
__global__ __launch_bounds__(512, 2) void qkv_gemm(
    const float* __restrict__ x,
    const unsigned char* __restrict__ wt2,
    unsigned short* __restrict__ qo,
    unsigned short* __restrict__ ko,
    unsigned short* __restrict__ vto) {

    __shared__ char smem[131072];   // A: 2 x 16KB @0; B: 2 x 48KB @32768

    const int tid = threadIdx.x;
    const int bm  = blockIdx.x;               // 0..255 (M tiles of 128)
    const int lane = tid & 63, wid = tid >> 6;
    const int lm = lane & 15, l4 = lane >> 4;

    f32x4 acc[8][3];
#pragma unroll
    for (int i = 0; i < 8; ++i)
#pragma unroll
        for (int j = 0; j < 3; ++j) acc[i][j] = (f32x4)0.f;

    // ---- A staging: thread -> row tid>>2, 16 consecutive f32 ----
    const int arow = tid >> 2;                // 0..127
    const int acb  = (tid & 3) * 16;          // f32 col base
    const float* xp = x + (size_t)(bm * 128 + arow) * 1024 + acb;
    const int aswz = (arow & 7) << 4;
    const int aw0 = arow * 128 + ((acb * 2) ^ aswz);
    const int aw1 = arow * 128 + ((acb * 2 + 16) ^ aswz);

    // ---- B staging (wave-private 48 rows, 6 x 1KB gload_lds) ----
    // chunk c: rows wid*48 + c*8 .. +7 ; lane l -> row +(l>>3), granule l&7
    const unsigned char* wsrc = wt2 +
        (size_t)(wid * 48 + (lane >> 3)) * 128 + (lane & 7) * 16;
    const int bldsrow = (wid * 48) * 128;     // byte offset of wave slab

    // ---- fragment rows ----
    int amr[8], bnr[3];
#pragma unroll
    for (int mi = 0; mi < 8; ++mi) amr[mi] = mi * 16 + lm;
#pragma unroll
    for (int ni = 0; ni < 3; ++ni) bnr[ni] = wid * 48 + ni * 16 + lm;

    // ---- prologue: A(0) regs, B(0) gloads; publish A(0) ----
    {
        f32x4 q0 = *(const f32x4*)(xp);
        f32x4 q1 = *(const f32x4*)(xp + 4);
        f32x4 q2 = *(const f32x4*)(xp + 8);
        f32x4 q3 = *(const f32x4*)(xp + 12);
#pragma unroll
        for (int c = 0; c < 6; ++c)
            GLOAD_LDS16(wsrc + c * 1024, smem + 32768 + bldsrow + c * 1024);
        asm volatile("s_waitcnt vmcnt(6)" ::: "memory");
        *(s16x8*)(smem + aw0) = cvt8(q0, q1);
        *(s16x8*)(smem + aw1) = cvt8(q2, q3);
        asm volatile("s_waitcnt lgkmcnt(0)" ::: "memory");
        __builtin_amdgcn_s_barrier();
    }

    for (int t = 0; t < 16; ++t) {
        const int ab = (t & 1) * 16384;
        const int bb = 32768 + (t & 1) * 49152;
        // ---- issue A(t+1) global loads (older than B(t+1) below) ----
        f32x4 n0, n1, n2, n3;
        if (t < 15) {
            const float* xq = xp + (t + 1) * 64;
            n0 = *(const f32x4*)(xq);
            n1 = *(const f32x4*)(xq + 4);
            n2 = *(const f32x4*)(xq + 8);
            n3 = *(const f32x4*)(xq + 12);
            // B(t) landed (own 6 gloads are the oldest; <=4 left = A(t+1))
            asm volatile("s_waitcnt vmcnt(4)" ::: "memory");
        } else {
            asm volatile("s_waitcnt vmcnt(0)" ::: "memory");
        }
        // ---- kkk = 0 ----
        {
            s16x8 af[8], bf[3];
#pragma unroll
            for (int mi = 0; mi < 8; ++mi)
                af[mi] = *(const s16x8*)(smem + ab + amr[mi] * 128 +
                           ((l4 * 16) ^ ((amr[mi] & 7) << 4)));
#pragma unroll
            for (int ni = 0; ni < 3; ++ni)
                bf[ni] = *(const s16x8*)(smem + bb + bnr[ni] * 128 +
                           ((l4 * 16) ^ ((bnr[ni] & 7) << 4)));
            __builtin_amdgcn_s_setprio(1);
#pragma unroll
            for (int ni = 0; ni < 3; ++ni)
#pragma unroll
                for (int mi = 0; mi < 8; ++mi)
                    acc[mi][ni] = __builtin_amdgcn_mfma_f32_16x16x32_bf16(
                        af[mi], bf[ni], acc[mi][ni], 0, 0, 0);
            __builtin_amdgcn_s_setprio(0);
        }
        // ---- issue B(t+1) gloads into the other buffer ----
        if (t < 15) {
            const unsigned char* ws = wsrc + (size_t)(t + 1) * 49152;
            char* bdst = smem + 32768 + ((t & 1) ^ 1) * 49152 + bldsrow;
#pragma unroll
            for (int c = 0; c < 6; ++c)
                GLOAD_LDS16(ws + c * 1024, bdst + c * 1024);
        }
        // ---- kkk = 1 ----
        {
            s16x8 af[8], bf[3];
#pragma unroll
            for (int mi = 0; mi < 8; ++mi)
                af[mi] = *(const s16x8*)(smem + ab + amr[mi] * 128 +
                           ((64 + l4 * 16) ^ ((amr[mi] & 7) << 4)));
#pragma unroll
            for (int ni = 0; ni < 3; ++ni)
                bf[ni] = *(const s16x8*)(smem + bb + bnr[ni] * 128 +
                           ((64 + l4 * 16) ^ ((bnr[ni] & 7) << 4)));
            __builtin_amdgcn_s_setprio(1);
#pragma unroll
            for (int ni = 0; ni < 3; ++ni)
#pragma unroll
                for (int mi = 0; mi < 8; ++mi)
                    acc[mi][ni] = __builtin_amdgcn_mfma_f32_16x16x32_bf16(
                        af[mi], bf[ni], acc[mi][ni], 0, 0, 0);
            __builtin_amdgcn_s_setprio(0);
        }
        // ---- publish A(t+1); B(t+1) stays in flight across the barrier ----
        if (t < 15) {
            asm volatile("s_waitcnt vmcnt(6)" ::: "memory");  // A(t+1) regs ready
            *(s16x8*)(smem + (ab ^ 16384) + aw0) = cvt8(n0, n1);
            *(s16x8*)(smem + (ab ^ 16384) + aw1) = cvt8(n2, n3);
            asm volatile("s_waitcnt lgkmcnt(0)" ::: "memory");
            __builtin_amdgcn_s_barrier();
        }
    }

    // ---- epilogue ----
#pragma unroll
    for (int mi = 0; mi < 8; ++mi) {
        int m0 = bm * 128 + mi * 16 + l4 * 4;  // global row (j adds 0..3)
#pragma unroll
        for (int ni = 0; ni < 3; ++ni) {
            int nb  = wid * 48 + ni * 16;
            int mat = nb >> 7;                 // 0=Q 1=K 2=V
            int col = (nb & 127) + lm;
            if (mat == 2) {
                int bb2 = m0 >> 8, tt = m0 & 255;
                s16x4 w4;
#pragma unroll
                for (int j = 0; j < 4; ++j) w4[j] = (short)f2bf(acc[mi][ni][j]);
                *(s16x4*)(vto + ((size_t)bb2 * 128 + col) * 256 + tt) = w4;
            } else {
                unsigned short* dst = (mat == 0) ? qo : ko;
#pragma unroll
                for (int j = 0; j < 4; ++j)
                    dst[(size_t)(m0 + j) * 128 + col] = f2bf(acc[mi][ni][j]);
            }
        }
    }
}

// ---------------------------------------------------------------------------
// Kernel 2: causal attention (unchanged; ~7µs).
// ---------------------------------------------------------------------------
__global__ __launch_bounds__(512) void attn(
    const unsigned short* __restrict__ q,
    const unsigned short* __restrict__ k,
    const unsigned short* __restrict__ vt,
    float* __restrict__ out) {

    __shared__ char pbuf[65536];               // 8 waves x [16][256] bf16

    const int tid = threadIdx.x, wid = tid >> 6, lane = tid & 63;
    const int lm = lane & 15, l4 = lane >> 4;
    const int b = blockIdx.x >> 1, qt = blockIdx.x & 1;
    const int qbase = qt << 7;
    const int t0 = qbase + wid * 16;
    const int nfrags = (qbase + 128) >> 4;     // 8 or 16
    const int nkf    = (qbase + 128) >> 5;     // 4 or 8

    const unsigned short* qrow = q + (size_t)(b * 256 + t0 + lm) * 128 + l4 * 8;
    s16x8 qf[4];
#pragma unroll
    for (int kf = 0; kf < 4; ++kf) qf[kf] = *(const s16x8*)(qrow + kf * 32);

    f32x4 sacc[16];
#pragma unroll
    for (int i = 0; i < 16; ++i) sacc[i] = (f32x4)0.f;

    const unsigned short* kbase = k + (size_t)(b * 256) * 128 + l4 * 8;
#pragma unroll
    for (int nf = 0; nf < 16; ++nf) {
        if (nf < nfrags) {
#pragma unroll
            for (int kf = 0; kf < 4; ++kf) {
                s16x8 a = *(const s16x8*)(kbase + (size_t)(nf * 16 + lm) * 128 + kf * 32);
                sacc[nf] = __builtin_amdgcn_mfma_f32_16x16x32_bf16(a, qf[kf], sacc[nf], 0, 0, 0);
            }
        }
    }

    const float scale = 0.08838834764831845f;  // 1/sqrt(128)
    const int tg = t0 + lm;
    float mx = -1e30f;
#pragma unroll
    for (int nf = 0; nf < 16; ++nf) {
        if (nf < nfrags) {
#pragma unroll
            for (int j = 0; j < 4; ++j) {
                int kv = nf * 16 + l4 * 4 + j;
                float s = sacc[nf][j] * scale;
                s = (kv > tg) ? -1e30f : s;
                sacc[nf][j] = s;
                mx = fmaxf(mx, s);
            }
        }
    }
    mx = fmaxf(mx, __shfl_xor(mx, 16));
    mx = fmaxf(mx, __shfl_xor(mx, 32));
    float sum = 0.f;
#pragma unroll
    for (int nf = 0; nf < 16; ++nf) {
        if (nf < nfrags) {
#pragma unroll
            for (int j = 0; j < 4; ++j) {
                float p = __expf(sacc[nf][j] - mx);
                sacc[nf][j] = p;
                sum += p;
            }
        }
    }
    sum += __shfl_xor(sum, 16);
    sum += __shfl_xor(sum, 32);
    float rinv = 1.0f / sum;

    char* pw = pbuf + wid * 8192 + lm * 512;
#pragma unroll
    for (int nf = 0; nf < 16; ++nf) {
        if (nf < nfrags) {
            s16x4 w;
#pragma unroll
            for (int j = 0; j < 4; ++j) w[j] = (short)f2bf(sacc[nf][j] * rinv);
            *(s16x4*)(pw + ((nf * 32 + l4 * 8) ^ ((lm & 7) << 4))) = w;
        }
    }
    asm volatile("s_waitcnt lgkmcnt(0)" ::: "memory");

    f32x4 oacc[8];
#pragma unroll
    for (int i = 0; i < 8; ++i) oacc[i] = (f32x4)0.f;

    const unsigned short* vbase = vt + (size_t)b * 32768 + l4 * 8;
#pragma unroll
    for (int kvf = 0; kvf < 8; ++kvf) {
        if (kvf < nkf) {
            s16x8 pf = *(const s16x8*)(pbuf + wid * 8192 + lm * 512 +
                        ((kvf * 64 + l4 * 16) ^ ((lm & 7) << 4)));
#pragma unroll
            for (int hf = 0; hf < 8; ++hf) {
                s16x8 a = *(const s16x8*)(vbase + (size_t)(hf * 16 + lm) * 256 + kvf * 32);
                oacc[hf] = __builtin_amdgcn_mfma_f32_16x16x32_bf16(a, pf, oacc[hf], 0, 0, 0);
            }
        }
    }

    float* ob = out + (size_t)(b * 256 + t0 + lm) * 128 + l4 * 4;
#pragma unroll
    for (int hf = 0; hf < 8; ++hf)
        *(f32x4*)(ob + hf * 16) = oacc[hf];
}

// ---------------------------------------------------------------------------
extern "C" void kernel_launch(void* const* d_in, const int* in_sizes, int n_in,
                              void* d_out, int out_size, void* d_ws, size_t ws_size,
                              hipStream_t stream) {
    const float* x  = (const float*)d_in[0];
    const float* Wq = (const float*)d_in[1];
    const float* Wk = (const float*)d_in[2];
    const float* Wv = (const float*)d_in[3];
    float* out = (float*)d_out;

    char* ws = (char*)d_ws;
    unsigned char*  wt = (unsigned char*)(ws);                     // 786432 B (swizzle-tiled)
    unsigned short* qb = (unsigned short*)(ws + 786432);           // 32768*128*2
    unsigned short* kb = (unsigned short*)(ws + 786432 + 8388608);
    unsigned short* vb = (unsigned short*)(ws + 786432 + 2 * 8388608);

    prep_wt<<<384, 256, 0, stream>>>(Wq, Wk, Wv, wt);
    qkv_gemm<<<256, 512, 0, stream>>>(x, wt, qb, kb, vb);
    attn<<<256, 512, 0, stream>>>(qb, kb, vb, out);
}

// Round 9
// 78.161 us; speedup vs baseline: 1.0616x; 1.0616x over previous
//
#include <hip/hip_runtime.h>

typedef float  f32x4  __attribute__((ext_vector_type(4)));
typedef short  s16x8  __attribute__((ext_vector_type(8)));
typedef short  s16x4  __attribute__((ext_vector_type(4)));

__device__ __forceinline__ unsigned short f2bf(float f) {
    unsigned int u = __float_as_uint(f);
    return (unsigned short)((u + 0x7FFFu + ((u >> 16) & 1u)) >> 16);
}

__device__ __forceinline__ s16x8 cvt8(f32x4 a, f32x4 b) {
    union { unsigned int u[4]; s16x8 v; } r;
    asm("v_cvt_pk_bf16_f32 %0, %1, %2" : "=v"(r.u[0]) : "v"(a[0]), "v"(a[1]));
    asm("v_cvt_pk_bf16_f32 %0, %1, %2" : "=v"(r.u[1]) : "v"(a[2]), "v"(a[3]));
    asm("v_cvt_pk_bf16_f32 %0, %1, %2" : "=v"(r.u[2]) : "v"(b[0]), "v"(b[1]));
    asm("v_cvt_pk_bf16_f32 %0, %1, %2" : "=v"(r.u[3]) : "v"(b[2]), "v"(b[3]));
    return r.v;
}

// barrier that fences only LDS (vmcnt stays in flight)
__device__ __forceinline__ void lds_barrier() {
    asm volatile("s_waitcnt lgkmcnt(0)" ::: "memory");
    __builtin_amdgcn_s_barrier();
    asm volatile("" ::: "memory");
}

// ---------------------------------------------------------------------------
// Kernel 0: wt3 = FRAGMENT-MAJOR bf16 weights.
// Fragment (n16 in [0,24), ks in [0,16), kkk in {0,1}) is one wave's exact
// MFMA B-operand: 64 lanes x 16B, lane-contiguous.  Element:
//   value = W_sel[k][n&127], n = n16*16 + (lane&15),
//   k = ks*64 + kkk*32 + (lane>>4)*8 + j.
// A single global_load_dwordx4 at (fragid*1024 + lane*16) IS the fragment —
// coalesced 1KB, straight from L2, no LDS, no barriers, no over-read.
// ---------------------------------------------------------------------------
__global__ void prep_wt(const float* __restrict__ Wq,
                        const float* __restrict__ Wk,
                        const float* __restrict__ Wv,
                        unsigned char* __restrict__ wt3) {
    int n = blockIdx.x;                       // 0..383
    const float* W = (n < 128) ? Wq : ((n < 256) ? Wk : Wv);
    int h = n & 127;
    int n16 = n >> 4, lmn = n & 15;
    for (int k = threadIdx.x; k < 1024; k += blockDim.x) {
        unsigned short v = f2bf(W[(size_t)k * 128 + h]);
        int ks = k >> 6, rem = k & 63;
        int kkk = rem >> 5, l4_ = (rem >> 3) & 3, j = rem & 7;
        int lane = l4_ * 16 + lmn;
        size_t off = (size_t)(n16 * 32 + ks * 2 + kkk) * 1024 + lane * 16 + j * 2;
        *(unsigned short*)(wt3 + off) = v;
    }
}

// ---------------------------------------------------------------------------
// Kernel 1: QKV GEMM — B entirely in registers (fragment-major wt3 from L2),
// LDS holds ONLY A (2x8KB swizzled double-buffer), ONE lgkm-only barrier per
// K-tile.  BM=64, BN=384 (x read exactly once), grid 512 = 2 desynced
// blocks/CU; 8 waves as 1M x 8N (wave = 64 rows x 48 cols, acc[4][3]).
// All vm waits are compiler-counted on register first-use; B(t+1) issued
// right after B(t)'s last MFMA; A(t+2) f32 loads issued a tile early.
// Race-free: B is wave-private regs; A is published via lgkmcnt(0)+barrier.
// Outputs: Q,K bf16 [B*T][128]; V transposed bf16 [B][128][256].
// ---------------------------------------------------------------------------
__global__ __launch_bounds__(512, 4) void qkv_gemm(
    const float* __restrict__ x,
    const unsigned char* __restrict__ wt3,
    unsigned short* __restrict__ qo,
    unsigned short* __restrict__ ko,
    unsigned short* __restrict__ vto) {

    __shared__ char smem[16384];              // A: 2 x [64][128B] swizzled

    const int tid = threadIdx.x;
    const int bm  = blockIdx.x;               // 0..511 (M tiles of 64)
    const int lane = tid & 63, wid = tid >> 6;
    const int lm = lane & 15, l4 = lane >> 4;

    f32x4 acc[4][3];
#pragma unroll
    for (int i = 0; i < 4; ++i)
#pragma unroll
        for (int j = 0; j < 3; ++j) acc[i][j] = (f32x4)0.f;

    // ---- A staging: thread -> row tid>>3, 8 consecutive f32 ----
    const int ar  = tid >> 3;
    const int ac8 = tid & 7;
    const float* xp = x + (size_t)(bm * 64 + ar) * 1024 + ac8 * 8;
    const int aw = ar * 128 + ((ac8 << 4) ^ ((ar & 7) << 4));

    // ---- B fragment geometry (wave-private, registers) ----
    const unsigned char* wb = wt3 + (size_t)lane * 16;
    int bqo[3];
#pragma unroll
    for (int ni = 0; ni < 3; ++ni) bqo[ni] = (wid * 3 + ni) * 32768; // *32*1024B

    // ---- A fragment read rows ----
    int arow[4];
#pragma unroll
    for (int mi = 0; mi < 4; ++mi) arow[mi] = mi * 16 + lm;

    // ---- prologue ----
    f32x4 pa0 = *(const f32x4*)(xp);
    f32x4 pa1 = *(const f32x4*)(xp + 4);
    s16x8 bq[6];
#pragma unroll
    for (int ni = 0; ni < 3; ++ni) {
        bq[ni * 2]     = *(const s16x8*)(wb + bqo[ni]);
        bq[ni * 2 + 1] = *(const s16x8*)(wb + bqo[ni] + 1024);
    }
    *(s16x8*)(smem + aw) = cvt8(pa0, pa1);
    pa0 = *(const f32x4*)(xp + 64);
    pa1 = *(const f32x4*)(xp + 68);
    lds_barrier();

    for (int t = 0; t < 16; ++t) {
        const int ab = (t & 1) * 8192;
        // ---- kkk = 0 ----
        {
            s16x8 af[4];
#pragma unroll
            for (int mi = 0; mi < 4; ++mi)
                af[mi] = *(const s16x8*)(smem + ab + arow[mi] * 128 +
                           ((l4 * 16) ^ ((arow[mi] & 7) << 4)));
            __builtin_amdgcn_s_setprio(1);
#pragma unroll
            for (int ni = 0; ni < 3; ++ni)
#pragma unroll
                for (int mi = 0; mi < 4; ++mi)
                    acc[mi][ni] = __builtin_amdgcn_mfma_f32_16x16x32_bf16(
                        af[mi], bq[ni * 2], acc[mi][ni], 0, 0, 0);
            __builtin_amdgcn_s_setprio(0);
        }
        // ---- kkk = 1 ----
        {
            s16x8 af[4];
#pragma unroll
            for (int mi = 0; mi < 4; ++mi)
                af[mi] = *(const s16x8*)(smem + ab + arow[mi] * 128 +
                           ((64 + l4 * 16) ^ ((arow[mi] & 7) << 4)));
            __builtin_amdgcn_s_setprio(1);
#pragma unroll
            for (int ni = 0; ni < 3; ++ni)
#pragma unroll
                for (int mi = 0; mi < 4; ++mi)
                    acc[mi][ni] = __builtin_amdgcn_mfma_f32_16x16x32_bf16(
                        af[mi], bq[ni * 2 + 1], acc[mi][ni], 0, 0, 0);
            __builtin_amdgcn_s_setprio(0);
        }
        // ---- stage next tile ----
        if (t < 15) {
            // B(t+1) fragments (after last use of bq(t); in flight across barrier)
            const unsigned char* wn = wb + (t + 1) * 2048;
#pragma unroll
            for (int ni = 0; ni < 3; ++ni) {
                bq[ni * 2]     = *(const s16x8*)(wn + bqo[ni]);
                bq[ni * 2 + 1] = *(const s16x8*)(wn + bqo[ni] + 1024);
            }
            // publish A(t+1) (regs loaded one tile ago)
            *(s16x8*)(smem + (ab ^ 8192) + aw) = cvt8(pa0, pa1);
            if (t < 14) {
                pa0 = *(const f32x4*)(xp + (t + 2) * 64);
                pa1 = *(const f32x4*)(xp + (t + 2) * 64 + 4);
            }
            lds_barrier();
        }
    }

    // ---- epilogue ----
#pragma unroll
    for (int mi = 0; mi < 4; ++mi) {
        int m0 = bm * 64 + mi * 16 + l4 * 4;   // global row (j adds 0..3)
#pragma unroll
        for (int ni = 0; ni < 3; ++ni) {
            int nb  = wid * 48 + ni * 16;
            int mat = nb >> 7;                 // 0=Q 1=K 2=V
            int col = (nb & 127) + lm;
            if (mat == 2) {
                int bb2 = m0 >> 8, tt = m0 & 255;
                s16x4 w4;
#pragma unroll
                for (int j = 0; j < 4; ++j) w4[j] = (short)f2bf(acc[mi][ni][j]);
                *(s16x4*)(vto + ((size_t)bb2 * 128 + col) * 256 + tt) = w4;
            } else {
                unsigned short* dst = (mat == 0) ? qo : ko;
#pragma unroll
                for (int j = 0; j < 4; ++j)
                    dst[(size_t)(m0 + j) * 128 + col] = f2bf(acc[mi][ni][j]);
            }
        }
    }
}

// ---------------------------------------------------------------------------
// Kernel 2: causal attention (unchanged from R7, correct; ~7µs).
// ---------------------------------------------------------------------------
__global__ __launch_bounds__(512) void attn(
    const unsigned short* __restrict__ q,
    const unsigned short* __restrict__ k,
    const unsigned short* __restrict__ vt,
    float* __restrict__ out) {

    __shared__ char pbuf[65536];               // 8 waves x [16][256] bf16

    const int tid = threadIdx.x, wid = tid >> 6, lane = tid & 63;
    const int lm = lane & 15, l4 = lane >> 4;
    const int b = blockIdx.x >> 1, qt = blockIdx.x & 1;
    const int qbase = qt << 7;
    const int t0 = qbase + wid * 16;
    const int nfrags = (qbase + 128) >> 4;
    const int nkf    = (qbase + 128) >> 5;

    const unsigned short* qrow = q + (size_t)(b * 256 + t0 + lm) * 128 + l4 * 8;
    s16x8 qf[4];
#pragma unroll
    for (int kf = 0; kf < 4; ++kf) qf[kf] = *(const s16x8*)(qrow + kf * 32);

    f32x4 sacc[16];
#pragma unroll
    for (int i = 0; i < 16; ++i) sacc[i] = (f32x4)0.f;

    const unsigned short* kbase = k + (size_t)(b * 256) * 128 + l4 * 8;
#pragma unroll
    for (int nf = 0; nf < 16; ++nf) {
        if (nf < nfrags) {
#pragma unroll
            for (int kf = 0; kf < 4; ++kf) {
                s16x8 a = *(const s16x8*)(kbase + (size_t)(nf * 16 + lm) * 128 + kf * 32);
                sacc[nf] = __builtin_amdgcn_mfma_f32_16x16x32_bf16(a, qf[kf], sacc[nf], 0, 0, 0);
            }
        }
    }

    const float scale = 0.08838834764831845f;  // 1/sqrt(128)
    const int tg = t0 + lm;
    float mx = -1e30f;
#pragma unroll
    for (int nf = 0; nf < 16; ++nf) {
        if (nf < nfrags) {
#pragma unroll
            for (int j = 0; j < 4; ++j) {
                int kv = nf * 16 + l4 * 4 + j;
                float s = sacc[nf][j] * scale;
                s = (kv > tg) ? -1e30f : s;
                sacc[nf][j] = s;
                mx = fmaxf(mx, s);
            }
        }
    }
    mx = fmaxf(mx, __shfl_xor(mx, 16));
    mx = fmaxf(mx, __shfl_xor(mx, 32));
    float sum = 0.f;
#pragma unroll
    for (int nf = 0; nf < 16; ++nf) {
        if (nf < nfrags) {
#pragma unroll
            for (int j = 0; j < 4; ++j) {
                float p = __expf(sacc[nf][j] - mx);
                sacc[nf][j] = p;
                sum += p;
            }
        }
    }
    sum += __shfl_xor(sum, 16);
    sum += __shfl_xor(sum, 32);
    float rinv = 1.0f / sum;

    char* pw = pbuf + wid * 8192 + lm * 512;
#pragma unroll
    for (int nf = 0; nf < 16; ++nf) {
        if (nf < nfrags) {
            s16x4 w;
#pragma unroll
            for (int j = 0; j < 4; ++j) w[j] = (short)f2bf(sacc[nf][j] * rinv);
            *(s16x4*)(pw + ((nf * 32 + l4 * 8) ^ ((lm & 7) << 4))) = w;
        }
    }
    asm volatile("s_waitcnt lgkmcnt(0)" ::: "memory");

    f32x4 oacc[8];
#pragma unroll
    for (int i = 0; i < 8; ++i) oacc[i] = (f32x4)0.f;

    const unsigned short* vbase = vt + (size_t)b * 32768 + l4 * 8;
#pragma unroll
    for (int kvf = 0; kvf < 8; ++kvf) {
        if (kvf < nkf) {
            s16x8 pf = *(const s16x8*)(pbuf + wid * 8192 + lm * 512 +
                        ((kvf * 64 + l4 * 16) ^ ((lm & 7) << 4)));
#pragma unroll
            for (int hf = 0; hf < 8; ++hf) {
                s16x8 a = *(const s16x8*)(vbase + (size_t)(hf * 16 + lm) * 256 + kvf * 32);
                oacc[hf] = __builtin_amdgcn_mfma_f32_16x16x32_bf16(a, pf, oacc[hf], 0, 0, 0);
            }
        }
    }

    float* ob = out + (size_t)(b * 256 + t0 + lm) * 128 + l4 * 4;
#pragma unroll
    for (int hf = 0; hf < 8; ++hf)
        *(f32x4*)(ob + hf * 16) = oacc[hf];
}

// ---------------------------------------------------------------------------
extern "C" void kernel_launch(void* const* d_in, const int* in_sizes, int n_in,
                              void* d_out, int out_size, void* d_ws, size_t ws_size,
                              hipStream_t stream) {
    const float* x  = (const float*)d_in[0];
    const float* Wq = (const float*)d_in[1];
    const float* Wk = (const float*)d_in[2];
    const float* Wv = (const float*)d_in[3];
    float* out = (float*)d_out;

    char* ws = (char*)d_ws;
    unsigned char*  wt = (unsigned char*)(ws);                     // 786432 B (fragment-major)
    unsigned short* qb = (unsigned short*)(ws + 786432);
    unsigned short* kb = (unsigned short*)(ws + 786432 + 8388608);
    unsigned short* vb = (unsigned short*)(ws + 786432 + 2 * 8388608);

    prep_wt<<<384, 256, 0, stream>>>(Wq, Wk, Wv, wt);
    qkv_gemm<<<512, 512, 0, stream>>>(x, wt, qb, kb, vb);
    attn<<<256, 512, 0, stream>>>(qb, kb, vb, out);
}